// Round 7
// baseline (49023.245 us; speedup 1.0000x reference)
//
#include <hip/hip_runtime.h>
#include <math.h>

#define R_DIM 4096
#define I_DIM 64
#define O_DIM 64
#define T_DIM 8192
#define NBLK  256
#define NTHR  512
#define RPB   16          // reservoir rows per block
#define LROWS 8           // rows kept in LDS

// raw barrier: waits LDS ops only -- deliberately NO vmcnt drain
#define LBAR() asm volatile("s_waitcnt lgkmcnt(0)\n\ts_barrier" ::: "memory")

// d_ws layout:
//   [0 .. 1KB)     : flags[256] u32   (flags[b] = steps published by block b)
//   [1KB .. 33KB)  : S double buffer  2 x 4096 f32
//   [64KB .. )     : Shist[T][R] (HIST mode only, 128 MB)

__global__ __launch_bounds__(NTHR, 2) void esn_persist(
    const float* __restrict__ X, const float* __restrict__ Wres,
    const float* __restrict__ Win, const float* __restrict__ Wout,
    float* __restrict__ out, unsigned* __restrict__ flags,
    float* __restrict__ S, float* __restrict__ Shist, int use_hist)
{
    __shared__ __align__(16) float wlds[LROWS * R_DIM];   // 128 KB weight tile
    __shared__ __align__(16) float sdata[R_DIM + I_DIM];  // state + x_t
    __shared__ float4 red4[8];

    const int tid  = threadIdx.x;
    const int b    = blockIdx.x;
    const int lane = tid & 63;
    const int w    = tid >> 6;        // wave 0..7
    const int rg   = tid >> 7;        // 0..3 : row group
    const int cg   = tid & 127;       // 0..127: column group
    const int R0   = b * RPB;

    // row map: acc0,1 -> LDS rows 2rg,2rg+1 ; acc2,3 -> REG rows 8+2rg,9+2rg
    const int rm0 = 2 * rg, rm1 = 2 * rg + 1;

    // ---- one-time: stage LDS half of W_res slice (rows 0..7, 128 KB) ----
    {
        const float4* wsrc = (const float4*)(Wres + (size_t)R0 * R_DIM);
        float4* wdst = (float4*)wlds;
#pragma unroll
        for (int k = 0; k < (LROWS * R_DIM / 4) / NTHR; ++k)
            wdst[k * NTHR + tid] = wsrc[k * NTHR + tid];
    }
    // ---- one-time: register half (rows 8..15), pinned via asm ----
    float4 wreg[2][8];
#pragma unroll
    for (int rr = 0; rr < 2; ++rr) {
        const float* rowp = Wres + (size_t)(R0 + 8 + 2 * rg + rr) * R_DIM + cg * 4;
#pragma unroll
        for (int i = 0; i < 8; ++i)
            wreg[rr][i] = *(const float4*)(rowp + i * 512);
    }
#pragma unroll
    for (int rr = 0; rr < 2; ++rr)
#pragma unroll
        for (int i = 0; i < 8; ++i)
            asm volatile("" : "+v"(wreg[rr][i].x), "+v"(wreg[rr][i].y),
                             "+v"(wreg[rr][i].z), "+v"(wreg[rr][i].w));

    float4 wi[4] = {};
    if (cg < 16) {
        wi[0] = *(const float4*)(Win + (size_t)(R0 + rm0) * I_DIM + cg * 4);
        wi[1] = *(const float4*)(Win + (size_t)(R0 + rm1) * I_DIM + cg * 4);
        wi[2] = *(const float4*)(Win + (size_t)(R0 + 8 + 2 * rg) * I_DIM + cg * 4);
        wi[3] = *(const float4*)(Win + (size_t)(R0 + 9 + 2 * rg) * I_DIM + cg * 4);
    }
    float4 wo4[4] = {};
    if (!use_hist && w == 1) {   // fallback readout wave: o = lane
#pragma unroll
        for (int j = 0; j < 4; ++j)
            wo4[j] = *(const float4*)(Wout + (size_t)lane * (I_DIM + R_DIM) + I_DIM + R0 + j * 4);
    }

    // flag indices this thread depends on (owners of its staged state words)
    const int f0 = tid >> 3;   // u64 word i has owner block i/8; words tid+k*512 -> f0+k*64

    for (int t = 0; t < T_DIM; ++t) {
        // issue x_t load early; consumed after the sweep
        float xval = 0.f;
        if (tid < I_DIM) xval = X[(size_t)t * I_DIM + tid];

        // ======== flag sweep: wait until this thread's 4 owner blocks published step t ========
        if (t) {
            const unsigned tgt = (unsigned)t;
            while (1) {
                unsigned a = __hip_atomic_load(&flags[f0      ], __ATOMIC_RELAXED, __HIP_MEMORY_SCOPE_AGENT);
                unsigned c = __hip_atomic_load(&flags[f0 + 64 ], __ATOMIC_RELAXED, __HIP_MEMORY_SCOPE_AGENT);
                unsigned d = __hip_atomic_load(&flags[f0 + 128], __ATOMIC_RELAXED, __HIP_MEMORY_SCOPE_AGENT);
                unsigned e = __hip_atomic_load(&flags[f0 + 192], __ATOMIC_RELAXED, __HIP_MEMORY_SCOPE_AGENT);
                if (__all(a >= tgt && c >= tgt && d >= tgt && e >= tgt)) break;
                __builtin_amdgcn_s_sleep(1);
            }
        }

        // ======== bulk stage S_{t-1} (16 KB) via coherent 8B loads ========
        {
            const unsigned long long* sprev =
                (const unsigned long long*)(S + ((t + 1) & 1) * R_DIM);
            unsigned long long v0 = __hip_atomic_load(&sprev[tid           ], __ATOMIC_RELAXED, __HIP_MEMORY_SCOPE_AGENT);
            unsigned long long v1 = __hip_atomic_load(&sprev[tid + 1 * NTHR], __ATOMIC_RELAXED, __HIP_MEMORY_SCOPE_AGENT);
            unsigned long long v2 = __hip_atomic_load(&sprev[tid + 2 * NTHR], __ATOMIC_RELAXED, __HIP_MEMORY_SCOPE_AGENT);
            unsigned long long v3 = __hip_atomic_load(&sprev[tid + 3 * NTHR], __ATOMIC_RELAXED, __HIP_MEMORY_SCOPE_AGENT);
            unsigned long long* dst = (unsigned long long*)sdata;
            dst[tid           ] = v0;
            dst[tid + 1 * NTHR] = v1;
            dst[tid + 2 * NTHR] = v2;
            dst[tid + 3 * NTHR] = v3;
            if (tid < I_DIM) sdata[R_DIM + tid] = xval;
        }
        LBAR();   // B1: sdata (state + x) visible to all waves

        // ======== COMPUTE: 2 LDS rows + 2 REG rows x 32 cols ========
        float acc0 = 0.f, acc1 = 0.f, acc2 = 0.f, acc3 = 0.f;
#pragma unroll
        for (int i = 0; i < 8; ++i) {
            const int col = cg * 4 + i * 512;
            float4 sv = *(const float4*)&sdata[col];
            float4 l0 = *(const float4*)&wlds[rm0 * R_DIM + col];
            float4 l1 = *(const float4*)&wlds[rm1 * R_DIM + col];
            acc0 += l0.x * sv.x + l0.y * sv.y + l0.z * sv.z + l0.w * sv.w;
            acc1 += l1.x * sv.x + l1.y * sv.y + l1.z * sv.z + l1.w * sv.w;
            acc2 += wreg[0][i].x * sv.x + wreg[0][i].y * sv.y + wreg[0][i].z * sv.z + wreg[0][i].w * sv.w;
            acc3 += wreg[1][i].x * sv.x + wreg[1][i].y * sv.y + wreg[1][i].z * sv.z + wreg[1][i].w * sv.w;
        }
        if (cg < 16) {
            float4 xv = *(const float4*)&sdata[R_DIM + cg * 4];
            acc0 += wi[0].x * xv.x + wi[0].y * xv.y + wi[0].z * xv.z + wi[0].w * xv.w;
            acc1 += wi[1].x * xv.x + wi[1].y * xv.y + wi[1].z * xv.z + wi[1].w * xv.w;
            acc2 += wi[2].x * xv.x + wi[2].y * xv.y + wi[2].z * xv.z + wi[2].w * xv.w;
            acc3 += wi[3].x * xv.x + wi[3].y * xv.y + wi[3].z * xv.z + wi[3].w * xv.w;
        }
#pragma unroll
        for (int d = 1; d < 64; d <<= 1) {
            acc0 += __shfl_xor(acc0, d);
            acc1 += __shfl_xor(acc1, d);
            acc2 += __shfl_xor(acc2, d);
            acc3 += __shfl_xor(acc3, d);
        }
        if (lane == 0) red4[w] = make_float4(acc0, acc1, acc2, acc3);
        LBAR();   // B2: red4 visible

        // ======== TAIL: wave0 publishes state then its own flag ========
        if (w == 0) {
            if (lane < RPB) {
                const int rgp = lane >> 2, rr = lane & 3;
                const int row = (rr < 2) ? (2 * rgp + rr) : (6 + 2 * rgp + rr);
                float pre = ((const float*)&red4[rgp * 2])[rr] + ((const float*)&red4[rgp * 2 + 1])[rr];
                float s = tanhf(pre);
                __hip_atomic_store(&S[(t & 1) * R_DIM + R0 + row], s,
                                   __ATOMIC_RELAXED, __HIP_MEMORY_SCOPE_AGENT);
                if (use_hist) Shist[(size_t)t * R_DIM + R0 + row] = s;
            }
            // state stores must reach the coherent point before the flag does
            asm volatile("s_waitcnt vmcnt(0)" ::: "memory");
            if (lane == 0)
                __hip_atomic_store(&flags[b], (unsigned)(t + 1),
                                   __ATOMIC_RELAXED, __HIP_MEMORY_SCOPE_AGENT);
        } else if (w == 1 && !use_hist) {
            // fallback in-loop readout (fire-and-forget atomics, off the barrier path)
            float s = 0.f;
            if (lane < RPB) {
                const int rgp = lane >> 2, rr = lane & 3;
                float pre = ((const float*)&red4[rgp * 2])[rr] + ((const float*)&red4[rgp * 2 + 1])[rr];
                s = tanhf(pre);
            }
            float y = 0.f;
#pragma unroll
            for (int j = 0; j < 16; ++j) {
                const int src = (j < 8) ? ((j >> 1) * 4 + (j & 1))
                                        : (((j - 8) >> 1) * 4 + 2 + ((j - 8) & 1));
                float sj = __shfl(s, src);
                y += ((const float*)wo4)[j] * sj;
            }
            __hip_atomic_fetch_add(&out[(size_t)t * O_DIM + lane], y,
                                   __ATOMIC_RELAXED, __HIP_MEMORY_SCOPE_AGENT);
        }
        // fallback mode: wave1 reads red4 ungated downstream -> fence re-writers
        if (!use_hist) LBAR();
        // hist mode: staging t+1 gates on our flag (set after wave0's red4 reads),
        // and all sdata reads precede B2 -> no trailing barrier needed
    }
}

// y_x[t,o] = Wout[o, :64] . x_t  -- plain writes, runs first
__global__ void esn_xpart(const float* __restrict__ X, const float* __restrict__ Wout,
                          float* __restrict__ out)
{
    const int idx = blockIdx.x * blockDim.x + threadIdx.x;  // t*64 + o
    const int t = idx >> 6, o = idx & 63;
    const float4* xr = (const float4*)(X + (size_t)t * I_DIM);
    const float4* wr = (const float4*)(Wout + (size_t)o * (I_DIM + R_DIM));
    float y = 0.f;
#pragma unroll
    for (int j = 0; j < 16; ++j) {
        float4 a = xr[j], b = wr[j];
        y += a.x * b.x + a.y * b.y + a.z * b.z + a.w * b.w;
    }
    out[idx] = y;
}

// HIST mode: out[t,o] += Wout[o, 64:] . Shist[t]  -- massively parallel, no atomics
__global__ void esn_readout(const float* __restrict__ Shist, const float* __restrict__ Wout,
                            float* __restrict__ out)
{
    const int idx = blockIdx.x * blockDim.x + threadIdx.x;  // t*64 + o
    const int t = idx >> 6, o = idx & 63;
    const float4* s4 = (const float4*)(Shist + (size_t)t * R_DIM);
    const float4* w4 = (const float4*)(Wout + (size_t)o * (I_DIM + R_DIM) + I_DIM);
    float y = 0.f;
#pragma unroll 4
    for (int j = 0; j < R_DIM / 4; ++j) {
        float4 a = s4[j], b = w4[j];
        y += a.x * b.x + a.y * b.y + a.z * b.z + a.w * b.w;
    }
    out[idx] += y;
}

extern "C" void kernel_launch(void* const* d_in, const int* in_sizes, int n_in,
                              void* d_out, int out_size, void* d_ws, size_t ws_size,
                              hipStream_t stream)
{
    (void)in_sizes; (void)n_in; (void)out_size;
    const float* X    = (const float*)d_in[0];
    const float* Win  = (const float*)d_in[1];
    const float* Wres = (const float*)d_in[2];
    const float* Wout = (const float*)d_in[3];
    float* out = (float*)d_out;

    unsigned* flags = (unsigned*)d_ws;
    float* S     = (float*)((char*)d_ws + 1024);
    float* Shist = (float*)((char*)d_ws + 65536);
    const size_t hist_bytes = (size_t)T_DIM * R_DIM * sizeof(float);
    const int use_hist = (ws_size >= 65536 + hist_bytes) ? 1 : 0;

    // reset flags + state double buffer every call
    hipMemsetAsync(d_ws, 0, 1024 + 2 * R_DIM * sizeof(float), stream);

    // x-part of readout initializes all of d_out
    esn_xpart<<<(T_DIM * O_DIM) / 256, 256, 0, stream>>>(X, Wout, out);

    void* args[] = { (void*)&X, (void*)&Wres, (void*)&Win, (void*)&Wout,
                     (void*)&out, (void*)&flags, (void*)&S, (void*)&Shist, (void*)&use_hist };
    hipLaunchCooperativeKernel((const void*)esn_persist, dim3(NBLK), dim3(NTHR),
                               args, 0, stream);

    if (use_hist)
        esn_readout<<<(T_DIM * O_DIM) / 256, 256, 0, stream>>>(Shist, Wout, out);
}

// Round 8
// 37044.824 us; speedup vs baseline: 1.3233x; 1.3233x over previous
//
#include <hip/hip_runtime.h>
#include <hip/hip_fp16.h>
#include <math.h>

#define R_DIM 4096
#define I_DIM 64
#define O_DIM 64
#define T_DIM 8192
#define NBLK  256
#define NTHR  512
#define RPB   16          // reservoir rows per block
#define LROWS 4           // rows kept in LDS (rest in registers)

// raw barrier: waits LDS ops only -- deliberately NO vmcnt drain
#define LBAR() asm volatile("s_waitcnt lgkmcnt(0)\n\ts_barrier" ::: "memory")

// d_ws layout:
//   [0 .. 32KB)   : pair double buffer  2 x 4096 x u32 {tag16, f16 val}
//   [64KB .. )    : Shist[T][R] f32 (HIST mode only, 128 MB)

__global__ __launch_bounds__(NTHR, 2) void esn_persist(
    const float* __restrict__ X, const float* __restrict__ Wres,
    const float* __restrict__ Win, const float* __restrict__ Wout,
    float* __restrict__ out, unsigned* __restrict__ pairs,
    float* __restrict__ Shist, int use_hist)
{
    __shared__ __align__(16) float wlds[LROWS * R_DIM];   // 64 KB weight tile
    __shared__ __align__(16) float sdata[R_DIM + I_DIM];  // state + x_t
    __shared__ float4 red4[8];

    const int tid  = threadIdx.x;
    const int b    = blockIdx.x;
    const int lane = tid & 63;
    const int w    = tid >> 6;        // wave 0..7
    const int rg   = tid >> 7;        // 0..3 : row group
    const int cg   = tid & 127;       // 0..127: column group
    const int R0   = b * RPB;

    // row map: acc0 -> LDS row rg ; acc1..3 -> REG rows 4+3rg+{0,1,2}
    // ---- one-time: stage LDS quarter of W_res slice (rows 0..3, 64 KB) ----
    {
        const float4* wsrc = (const float4*)(Wres + (size_t)R0 * R_DIM);
        float4* wdst = (float4*)wlds;
#pragma unroll
        for (int k = 0; k < (LROWS * R_DIM / 4) / NTHR; ++k)
            wdst[k * NTHR + tid] = wsrc[k * NTHR + tid];
    }
    // ---- one-time: register rows (4..15), pinned via asm ----
    float4 wreg[3][8];
#pragma unroll
    for (int rr = 0; rr < 3; ++rr) {
        const float* rowp = Wres + (size_t)(R0 + 4 + 3 * rg + rr) * R_DIM + cg * 4;
#pragma unroll
        for (int i = 0; i < 8; ++i)
            wreg[rr][i] = *(const float4*)(rowp + i * 512);
    }
#pragma unroll
    for (int rr = 0; rr < 3; ++rr)
#pragma unroll
        for (int i = 0; i < 8; ++i)
            asm volatile("" : "+v"(wreg[rr][i].x), "+v"(wreg[rr][i].y),
                             "+v"(wreg[rr][i].z), "+v"(wreg[rr][i].w));

    float4 wi[4] = {};
    if (cg < 16) {
        wi[0] = *(const float4*)(Win + (size_t)(R0 + rg) * I_DIM + cg * 4);
        wi[1] = *(const float4*)(Win + (size_t)(R0 + 4 + 3 * rg) * I_DIM + cg * 4);
        wi[2] = *(const float4*)(Win + (size_t)(R0 + 5 + 3 * rg) * I_DIM + cg * 4);
        wi[3] = *(const float4*)(Win + (size_t)(R0 + 6 + 3 * rg) * I_DIM + cg * 4);
    }
    float4 wo4[4] = {};
    if (!use_hist && w == 1) {   // fallback readout wave: o = lane
#pragma unroll
        for (int j = 0; j < 4; ++j)
            wo4[j] = *(const float4*)(Wout + (size_t)lane * (I_DIM + R_DIM) + I_DIM + R0 + j * 4);
    }

    for (int t = 0; t < T_DIM; ++t) {
        // ======== STAGE: all 8 waves poll+stage 512 u32 pairs each ========
        if (tid < I_DIM) sdata[R_DIM + tid] = X[(size_t)t * I_DIM + tid];
        {
            // buf[(t+1)&1] holds S_{t-1} tagged t (tag in high 16 bits)
            unsigned* rbuf = pairs + ((t + 1) & 1) * R_DIM;
            const int base = w * 512 + lane;
            const unsigned tagmin = (unsigned)t;
            float vals[8];
            unsigned got = 0;
            while (got != 0xFFu) {
#pragma unroll
                for (int k = 0; k < 8; ++k) {
                    if (!(got & (1u << k))) {
                        unsigned p = __hip_atomic_load(&rbuf[base + k * 64],
                                      __ATOMIC_RELAXED, __HIP_MEMORY_SCOPE_AGENT);
                        if ((p >> 16) >= tagmin) {
                            vals[k] = __half2float(__ushort_as_half((unsigned short)(p & 0xFFFFu)));
                            got |= 1u << k;
                        }
                    }
                }
            }
#pragma unroll
            for (int k = 0; k < 8; ++k) sdata[base + k * 64] = vals[k];
        }
        LBAR();   // B1: sdata (state + x) visible to all waves

        // ======== COMPUTE: 1 LDS row + 3 REG rows x 32 cols/thread ========
        float acc0 = 0.f, acc1 = 0.f, acc2 = 0.f, acc3 = 0.f;
#pragma unroll
        for (int i = 0; i < 8; ++i) {
            const int col = cg * 4 + i * 512;
            float4 sv = *(const float4*)&sdata[col];
            float4 l0 = *(const float4*)&wlds[rg * R_DIM + col];
            acc0 += l0.x * sv.x + l0.y * sv.y + l0.z * sv.z + l0.w * sv.w;
            acc1 += wreg[0][i].x * sv.x + wreg[0][i].y * sv.y + wreg[0][i].z * sv.z + wreg[0][i].w * sv.w;
            acc2 += wreg[1][i].x * sv.x + wreg[1][i].y * sv.y + wreg[1][i].z * sv.z + wreg[1][i].w * sv.w;
            acc3 += wreg[2][i].x * sv.x + wreg[2][i].y * sv.y + wreg[2][i].z * sv.z + wreg[2][i].w * sv.w;
        }
        if (cg < 16) {
            float4 xv = *(const float4*)&sdata[R_DIM + cg * 4];
            acc0 += wi[0].x * xv.x + wi[0].y * xv.y + wi[0].z * xv.z + wi[0].w * xv.w;
            acc1 += wi[1].x * xv.x + wi[1].y * xv.y + wi[1].z * xv.z + wi[1].w * xv.w;
            acc2 += wi[2].x * xv.x + wi[2].y * xv.y + wi[2].z * xv.z + wi[2].w * xv.w;
            acc3 += wi[3].x * xv.x + wi[3].y * xv.y + wi[3].z * xv.z + wi[3].w * xv.w;
        }
#pragma unroll
        for (int d = 1; d < 64; d <<= 1) {
            acc0 += __shfl_xor(acc0, d);
            acc1 += __shfl_xor(acc1, d);
            acc2 += __shfl_xor(acc2, d);
            acc3 += __shfl_xor(acc3, d);
        }
        if (lane == 0) red4[w] = make_float4(acc0, acc1, acc2, acc3);
        LBAR();   // B2: red4 visible

        // ======== TAIL: wave0 finishes rows, publishes tagged fp16 pairs ========
        if (w == 0) {
            // same-address ordering safety for prior-epoch stores (cheap, wave0 only)
            asm volatile("s_waitcnt vmcnt(0)" ::: "memory");
            if (lane < RPB) {
                const int rgp = lane >> 2, rr = lane & 3;
                const int row = (rr == 0) ? rgp : (4 + 3 * rgp + (rr - 1));
                float pre = ((const float*)&red4[rgp * 2])[rr] + ((const float*)&red4[rgp * 2 + 1])[rr];
                float s = tanhf(pre);
                unsigned pack = ((unsigned)(t + 1) << 16)
                              | (unsigned)__half_as_ushort(__float2half(s));
                __hip_atomic_store(&pairs[(t & 1) * R_DIM + R0 + row], pack,
                                   __ATOMIC_RELAXED, __HIP_MEMORY_SCOPE_AGENT);
                if (use_hist) Shist[(size_t)t * R_DIM + R0 + row] = s;
            }
        } else if (w == 1 && !use_hist) {
            // fallback in-loop readout (fire-and-forget atomics)
            float s = 0.f;
            if (lane < RPB) {
                const int rgp = lane >> 2, rr = lane & 3;
                float pre = ((const float*)&red4[rgp * 2])[rr] + ((const float*)&red4[rgp * 2 + 1])[rr];
                s = tanhf(pre);
            }
            float y = 0.f;
#pragma unroll
            for (int j = 0; j < 16; ++j) {
                const int src = (j < 4) ? (4 * j)
                                        : (4 * ((j - 4) / 3) + ((j - 4) % 3) + 1);
                float sj = __shfl(s, src);
                y += ((const float*)wo4)[j] * sj;
            }
            __hip_atomic_fetch_add(&out[(size_t)t * O_DIM + lane], y,
                                   __ATOMIC_RELAXED, __HIP_MEMORY_SCOPE_AGENT);
        }
        // fallback mode: wave1 reads red4 ungated downstream -> fence re-writers
        if (!use_hist) LBAR();
        // hist mode: t+1 staging gates on our publish (after red4 reads) -> no barrier
    }
}

// y_x[t,o] = Wout[o, :64] . x_t  -- plain writes, runs first
__global__ void esn_xpart(const float* __restrict__ X, const float* __restrict__ Wout,
                          float* __restrict__ out)
{
    const int idx = blockIdx.x * blockDim.x + threadIdx.x;  // t*64 + o
    const int t = idx >> 6, o = idx & 63;
    const float4* xr = (const float4*)(X + (size_t)t * I_DIM);
    const float4* wr = (const float4*)(Wout + (size_t)o * (I_DIM + R_DIM));
    float y = 0.f;
#pragma unroll
    for (int j = 0; j < 16; ++j) {
        float4 a = xr[j], b = wr[j];
        y += a.x * b.x + a.y * b.y + a.z * b.z + a.w * b.w;
    }
    out[idx] = y;
}

// HIST mode: out[t,o] += Wout[o, 64:] . Shist[t]  -- massively parallel, no atomics
__global__ void esn_readout(const float* __restrict__ Shist, const float* __restrict__ Wout,
                            float* __restrict__ out)
{
    const int idx = blockIdx.x * blockDim.x + threadIdx.x;  // t*64 + o
    const int t = idx >> 6, o = idx & 63;
    const float4* s4 = (const float4*)(Shist + (size_t)t * R_DIM);
    const float4* w4 = (const float4*)(Wout + (size_t)o * (I_DIM + R_DIM) + I_DIM);
    float y = 0.f;
#pragma unroll 4
    for (int j = 0; j < R_DIM / 4; ++j) {
        float4 a = s4[j], b = w4[j];
        y += a.x * b.x + a.y * b.y + a.z * b.z + a.w * b.w;
    }
    out[idx] += y;
}

extern "C" void kernel_launch(void* const* d_in, const int* in_sizes, int n_in,
                              void* d_out, int out_size, void* d_ws, size_t ws_size,
                              hipStream_t stream)
{
    (void)in_sizes; (void)n_in; (void)out_size;
    const float* X    = (const float*)d_in[0];
    const float* Win  = (const float*)d_in[1];
    const float* Wres = (const float*)d_in[2];
    const float* Wout = (const float*)d_in[3];
    float* out = (float*)d_out;

    unsigned* pairs = (unsigned*)d_ws;
    float* Shist = (float*)((char*)d_ws + 65536);
    const size_t hist_bytes = (size_t)T_DIM * R_DIM * sizeof(float);
    const int use_hist = (ws_size >= 65536 + hist_bytes) ? 1 : 0;

    // reset pair tags every call (stale tags would break polling)
    hipMemsetAsync(d_ws, 0, 2 * R_DIM * sizeof(unsigned), stream);

    // x-part of readout initializes all of d_out
    esn_xpart<<<(T_DIM * O_DIM) / 256, 256, 0, stream>>>(X, Wout, out);

    void* args[] = { (void*)&X, (void*)&Wres, (void*)&Win, (void*)&Wout,
                     (void*)&out, (void*)&pairs, (void*)&Shist, (void*)&use_hist };
    hipLaunchCooperativeKernel((const void*)esn_persist, dim3(NBLK), dim3(NTHR),
                               args, 0, stream);

    if (use_hist)
        esn_readout<<<(T_DIM * O_DIM) / 256, 256, 0, stream>>>(Shist, Wout, out);
}